// Round 2
// baseline (1096.216 us; speedup 1.0000x reference)
//
#include <hip/hip_runtime.h>

#define KN    32
#define DIN   128
#define TBL   2048   // dt-table resolution; entries TBL+1, linear interp err ~1e-7
#define GRID  2048   // persistent blocks: ~8 per CU

// raw barrier: cross-wave LDS ordering WITHOUT the hipcc vmcnt(0) drain, so
// prefetched global loads stay in flight across phase barriers (m201 pattern).
#define BAR() do { asm volatile("s_waitcnt lgkmcnt(0)" ::: "memory"); \
                   __builtin_amdgcn_s_barrier(); } while (0)

// ---------------------------------------------------------------------------
// Kernel 1: fold W2@W4 -> u[128], W1@W4 -> v[128], and build the delta-time
// table: table[i] = b4 + sum_e W4[e] * sigmoid((i/TBL) * W3[e]).
// ---------------------------------------------------------------------------
__global__ void precompute(const float* __restrict__ W1,
                           const float* __restrict__ W2,
                           const float* __restrict__ W3,
                           const float* __restrict__ W4,
                           const float* __restrict__ b4,
                           float* __restrict__ uv,      // u[128] ++ v[128]
                           float* __restrict__ table)   // [TBL+1]
{
    const int t = blockIdx.x * blockDim.x + threadIdx.x;
    if (blockIdx.x == 0) {
        const int tid = threadIdx.x;
        if (tid < DIN) {
            const float* row = W2 + tid * DIN;
            float acc = 0.f;
            for (int e = 0; e < DIN; ++e) acc += row[e] * W4[e];
            uv[tid] = acc;                       // u[d] = sum_e W2[d,e]*W4[e]
        } else {
            const int d = tid - DIN;
            const float* row = W1 + d * DIN;
            float acc = 0.f;
            for (int e = 0; e < DIN; ++e) acc += row[e] * W4[e];
            uv[DIN + d] = acc;                   // v[d] = sum_e W1[d,e]*W4[e]
        }
    }
    for (int i = t; i <= TBL; i += gridDim.x * blockDim.x) {
        const float x = (float)i * (1.0f / (float)TBL);
        float acc = b4[0];
        for (int e = 0; e < DIN; ++e)
            acc += W4[e] / (1.0f + __expf(-x * W3[e]));
        table[i] = acc;
    }
}

// ---------------------------------------------------------------------------
// Kernel 2: PERSISTENT blocks. Each block owns n in [n0,n1) (~25 rows) and
// runs a depth-2 register pipeline: while computing row n, the global loads
// for row n+1 (neigh tile + dt + self) are already in flight. Raw barriers
// keep those loads outstanding across the phase syncs. This removes the
// 50000-workgroup dispatch serialization and the per-block cold-start
// latency that capped the previous versions at ~1.7 TB/s.
// ---------------------------------------------------------------------------
__global__ __launch_bounds__(256) void attn_agg(
    const float* __restrict__ self_vecs,   // [N,128]
    const float* __restrict__ neigh_vecs,  // [N,32,128]
    const float* __restrict__ dt,          // [N,32]
    const float* __restrict__ uv,          // u[128] ++ v[128]
    const float* __restrict__ table,       // [TBL+1]
    float* __restrict__ out,               // [N,128]
    float* __restrict__ score_out,         // [N,32]
    int N, int per_blk)
{
    __shared__ float s_p[KN * 33];                    // score partials [k][q], +1 pad
    __shared__ __align__(16) float s_part[8 * DIN];   // weighted partials [g][e]
    __shared__ float s_score[KN];
    __shared__ float s_qw4;

    const int tid = threadIdx.x;
    const int g   = tid >> 5;     // 0..7
    const int q   = tid & 31;     // 0..31

    const int n0 = blockIdx.x * per_blk;
    const int n1 = min(n0 + per_blk, N);
    if (n0 >= n1) return;

    // ---- loop-invariant params (L1-hot after first touch) ----
    const float4 u4 = *(const float4*)(uv + 4 * q);
    float vl0 = 0.f, vl1 = 0.f;
    if (tid < 64) { vl0 = uv[DIN + tid]; vl1 = uv[DIN + tid + 64]; }

    // ---- prologue: issue loads for n0 ----
    const float4* gsrc = (const float4*)(neigh_vecs + (size_t)n0 * KN * DIN);
    float4 c0 = gsrc[tid];          // row g      , cols 4q..4q+3
    float4 c1 = gsrc[tid + 256];    // row g + 8
    float4 c2 = gsrc[tid + 512];    // row g + 16
    float4 c3 = gsrc[tid + 768];    // row g + 24
    float dt_c = 0.f, sv0_c = 0.f, sv1_c = 0.f;
    if (tid < 64) {
        const float* sv = self_vecs + (size_t)n0 * DIN;
        sv0_c = sv[tid];
        sv1_c = sv[tid + 64];
        if (tid < 32) dt_c = dt[(size_t)n0 * KN + tid];
    }

    for (int n = n0; n < n1; ++n) {
        // ---- issue next row's loads; they stay in flight across all barriers
        float4 x0 = {0,0,0,0}, x1 = {0,0,0,0}, x2 = {0,0,0,0}, x3 = {0,0,0,0};
        float dt_n = 0.f, sv0_n = 0.f, sv1_n = 0.f;
        if (n + 1 < n1) {
            const float4* gn = (const float4*)(neigh_vecs + (size_t)(n + 1) * KN * DIN);
            x0 = gn[tid];
            x1 = gn[tid + 256];
            x2 = gn[tid + 512];
            x3 = gn[tid + 768];
            if (tid < 64) {
                const float* svn = self_vecs + (size_t)(n + 1) * DIN;
                sv0_n = svn[tid];
                sv1_n = svn[tid + 64];
                if (tid < 32) dt_n = dt[(size_t)(n + 1) * KN + tid];
            }
        }

        // ---- Phase A: qW4 (wave 0) + score dot partials ----
        if (tid < 64) {
            float qp = sv0_c * vl0 + sv1_c * vl1;
            #pragma unroll
            for (int off = 32; off > 0; off >>= 1)
                qp += __shfl_down(qp, off, 64);
            if (tid == 0) s_qw4 = qp;
        }
        s_p[ g       * 33 + q] = c0.x*u4.x + c0.y*u4.y + c0.z*u4.z + c0.w*u4.w;
        s_p[(g +  8) * 33 + q] = c1.x*u4.x + c1.y*u4.y + c1.z*u4.z + c1.w*u4.w;
        s_p[(g + 16) * 33 + q] = c2.x*u4.x + c2.y*u4.y + c2.z*u4.z + c2.w*u4.w;
        s_p[(g + 24) * 33 + q] = c3.x*u4.x + c3.y*u4.y + c3.z*u4.z + c3.w*u4.w;
        BAR();

        // ---- Phase B: scores + softmax (wave 0: 2 lanes per k) ----
        if (tid < 64) {
            const int k = tid & 31;
            const int h = tid >> 5;
            const float* pr = s_p + k * 33 + h * 16;   // (k+16h+j)%32: 2-way, free
            float s = 0.f;
            #pragma unroll
            for (int j = 0; j < 16; ++j) s += pr[j];
            s += __shfl_down(s, 32, 64);               // lanes<32 hold full dot_k
            if (tid < 32) {
                float fx = fminf(fmaxf(dt_c, 0.0f), 1.0f) * (float)TBL;
                int   i0 = min((int)fx, TBL - 1);
                const float fr = fx - (float)i0;
                const float t0 = table[i0];
                const float t1 = table[i0 + 1];
                float sp = s_qw4 + s + t0 + fr * (t1 - t0);   // b4 folded in table
                sp = sp > 0.f ? sp : 0.f;
                float mx = sp;
                #pragma unroll
                for (int off = 16; off > 0; off >>= 1)
                    mx = fmaxf(mx, __shfl_xor(mx, off, 32));
                const float ex = __expf(sp - mx);
                float sm = ex;
                #pragma unroll
                for (int off = 16; off > 0; off >>= 1)
                    sm += __shfl_xor(sm, off, 32);
                const float sc = ex / sm;
                s_score[k] = sc;
                score_out[(size_t)n * KN + k] = sc;
            }
        }
        BAR();

        // ---- Phase C: weighted sum from registers ----
        {
            const float sc0 = s_score[g];        // 2 addrs/wave: broadcast, free
            const float sc1 = s_score[g + 8];
            const float sc2 = s_score[g + 16];
            const float sc3 = s_score[g + 24];
            float4 po;
            po.x = sc0*c0.x + sc1*c1.x + sc2*c2.x + sc3*c3.x;
            po.y = sc0*c0.y + sc1*c1.y + sc2*c2.y + sc3*c3.y;
            po.z = sc0*c0.z + sc1*c1.z + sc2*c2.z + sc3*c3.z;
            po.w = sc0*c0.w + sc1*c1.w + sc2*c2.w + sc3*c3.w;
            *(float4*)(s_part + g * DIN + 4 * q) = po;
        }
        BAR();

        // ---- Phase D: combine 8 g-partials, store ----
        if (tid < DIN) {
            float acc = 0.f;
            #pragma unroll
            for (int gg = 0; gg < 8; ++gg) acc += s_part[gg * DIN + tid];
            out[(size_t)n * DIN + tid] = acc;
        }
        // (D's LDS reads are drained by this wave's lgkmcnt(0) at next BAR;
        //  next writer of s_part is Phase C, two barriers later — race-free.)

        // ---- rotate pipeline: waits on next-row loads land HERE, after
        //      having been hidden under Phases A-D.
        c0 = x0; c1 = x1; c2 = x2; c3 = x3;
        dt_c = dt_n; sv0_c = sv0_n; sv1_c = sv1_n;
    }
}

// ---------------------------------------------------------------------------
extern "C" void kernel_launch(void* const* d_in, const int* in_sizes, int n_in,
                              void* d_out, int out_size, void* d_ws, size_t ws_size,
                              hipStream_t stream) {
    const float* self_vecs = (const float*)d_in[0];
    const float* neigh     = (const float*)d_in[1];
    const float* dtim      = (const float*)d_in[2];
    const float* W1        = (const float*)d_in[3];
    const float* W2        = (const float*)d_in[4];
    const float* W3        = (const float*)d_in[5];
    const float* W4        = (const float*)d_in[6];
    const float* b4        = (const float*)d_in[7];

    const int N = in_sizes[0] / DIN;           // 50000
    float* uv    = (float*)d_ws;               // 256 floats
    float* table = uv + 256;                   // TBL+1 floats
    float* out       = (float*)d_out;          // [N,128]
    float* score_out = out + (size_t)N * DIN;  // [N,32]

    const int per_blk = (N + GRID - 1) / GRID; // ~25

    precompute<<<9, 256, 0, stream>>>(W1, W2, W3, W4, b4, uv, table);
    attn_agg<<<GRID, 256, 0, stream>>>(self_vecs, neigh, dtim, uv, table,
                                       out, score_out, N, per_blk);
}